// Round 8
// baseline (241.977 us; speedup 1.0000x reference)
//
#include <hip/hip_runtime.h>
#include <stdint.h>

typedef unsigned long long u64;
typedef uint32_t u32;

#define BB  32
#define CC  256
#define HH  56
#define WW  56
#define OHH 28
#define OWW 28
#define NPIX (BB*OHH*OWW)   // 25088
#define PACKBLKS 3136       // 802816/256
#define FGRID (BB*OHH)      // 896 fused blocks

// ---------------- Kernel 0: pack sign(x+beta1)+avgpool (blocks 0..3135)
//                  + weight prep/alpha/stats+barrier zero (blocks 3136..3647) --------------
__global__ __launch_bounds__(256) void rrb_prep_pack(const float* __restrict__ x,
                                                     const float* __restrict__ rsb1,
                                                     const float* __restrict__ w1,
                                                     const float* __restrict__ w2,
                                                     u32* __restrict__ xb, float* __restrict__ pool,
                                                     u32* __restrict__ wp1, u32* __restrict__ wp2,
                                                     float* __restrict__ alpha1, float* __restrict__ alpha2,
                                                     u32* __restrict__ stats_zero, int* __restrict__ bar) {
    if (blockIdx.x >= PACKBLKS) {
        __shared__ float red[256];
        int pb = blockIdx.x - PACKBLKS;     // 0..511
        int co = pb & 255;
        int t = threadIdx.x;                // ci
        int wid = t >> 6, lane = t & 63;
        if (pb == 0) {
            #pragma unroll
            for (int k = 0; k < 6; ++k) stats_zero[k * 256 + t] = 0u;
            if (t == 0) *bar = 0;
        }
        float asum = 0.f;
        if (pb < 256) {
            const float* wr = w1 + (size_t)co * 2304 + (size_t)t * 9;
            float v[9];
            #pragma unroll
            for (int k = 0; k < 9; ++k) { v[k] = wr[k]; asum += fabsf(v[k]); }
            #pragma unroll
            for (int k = 0; k < 9; ++k) {
                u64 m = __ballot(v[k] > 0.f);
                if (lane == 0)
                    *(u64*)&wp1[((size_t)co * 9 + k) * 8 + 2 * wid] = m;
            }
        } else {
            float v = w2[co * 256 + t];
            asum = fabsf(v);
            u64 m = __ballot(v > 0.f);
            if (lane == 0) *(u64*)&wp2[co * 8 + 2 * wid] = m;
        }
        red[t] = asum; __syncthreads();
        for (int st = 128; st > 0; st >>= 1) {
            if (t < st) red[t] += red[t + st];
            __syncthreads();
        }
        if (t == 0) {
            if (pb < 256) alpha1[co] = red[0] / 2304.f;
            else          alpha2[co] = red[0] / 256.f;
        }
        return;
    }
    // ---- pack path: thread = (j-word, n, oh, ow, s-subslice) ----
    int i = blockIdx.x * 256 + threadIdx.x;   // 802816
    int s  = i & 3;
    int i2 = i >> 2;
    int ow = i2 % OWW;
    int i3 = i2 / OWW;
    int oh = i3 % OHH;
    int i4 = i3 / OHH;
    int n  = i4 & 31;
    int j  = i4 >> 5;
    int c0 = 32 * j + 8 * s;
    const float* base = x + (((size_t)(n * CC + c0) * HH + 2 * oh) * WW + 2 * ow);

    float2 a0[8], a1[8];
    #pragma unroll
    for (int cc = 0; cc < 8; ++cc) {
        const float* p = base + (size_t)cc * (HH * WW);
        a0[cc] = *(const float2*)p;
        a1[cc] = *(const float2*)(p + WW);
    }
    float4 b0 = *(const float4*)&rsb1[c0];
    float4 b1 = *(const float4*)&rsb1[c0 + 4];

    u32 w00 = 0, w01 = 0, w10 = 0, w11 = 0;
    float pv[8];
    #pragma unroll
    for (int cc = 0; cc < 8; ++cc) {
        float b = (cc < 4) ? ((const float*)&b0)[cc] : ((const float*)&b1)[cc - 4];
        w00 |= (u32)(a0[cc].x + b > 0.f) << cc;
        w01 |= (u32)(a0[cc].y + b > 0.f) << cc;
        w10 |= (u32)(a1[cc].x + b > 0.f) << cc;
        w11 |= (u32)(a1[cc].y + b > 0.f) << cc;
        pv[cc] = (a0[cc].x + a0[cc].y + a1[cc].x + a1[cc].y) * 0.25f;
    }
    w00 <<= 8 * s; w01 <<= 8 * s; w10 <<= 8 * s; w11 <<= 8 * s;
    w00 |= __shfl_xor(w00, 1); w00 |= __shfl_xor(w00, 2);
    w01 |= __shfl_xor(w01, 1); w01 |= __shfl_xor(w01, 2);
    w10 |= __shfl_xor(w10, 1); w10 |= __shfl_xor(w10, 2);
    w11 |= __shfl_xor(w11, 1); w11 |= __shfl_xor(w11, 2);

    float* pp = pool + ((size_t)(n * OHH + oh) * OWW + ow) * CC + c0;
    *(float4*)&pp[0] = make_float4(pv[0], pv[1], pv[2], pv[3]);
    *(float4*)&pp[4] = make_float4(pv[4], pv[5], pv[6], pv[7]);

    u32* xo = xb + (((size_t)(n * HH + 2 * oh) * WW + 2 * ow) * 8) + j;
    u32 wsel = (s == 0) ? w00 : (s == 1) ? w01 : (s == 2) ? w10 : w11;
    int off = (s == 0) ? 0 : (s == 1) ? 8 : (s == 2) ? WW * 8 : WW * 8 + 8;
    xo[off] = wsel;
}

// ---- device-scope spin barrier (all FGRID blocks co-resident by occupancy arithmetic) ----
__device__ __forceinline__ void gbar(int* cnt, int target) {
    __syncthreads();
    if (threadIdx.x == 0) {
        __threadfence();   // release my atomics/stores to device scope
        __hip_atomic_fetch_add(cnt, 1, __ATOMIC_ACQ_REL, __HIP_MEMORY_SCOPE_AGENT);
        int guard = 0;
        while (__hip_atomic_load(cnt, __ATOMIC_ACQUIRE, __HIP_MEMORY_SCOPE_AGENT) < target) {
            __builtin_amdgcn_s_sleep(8);
            if (++guard > (1 << 22)) break;   // bounded bail-out: fail, don't hang
        }
    }
    __syncthreads();
}

// ---- BN finalize from exact integer stats ----
__device__ __forceinline__ void bn_fold_v(int sv, u64 qv, float al_, float g_, float be_,
                                          float& a, float& b) {
    const double N = (double)NPIX;
    double s = (double)sv;
    double q = (double)qv;
    double mS = s / N;
    double vS = q / N - mS * mS;
    double al = (double)al_;
    double scale = (double)g_ / sqrt(al * al * vS + 1e-5);
    a = (float)(al * scale);
    b = (float)((double)be_ - al * mS * scale);
}

// ---------------- Persistent fused kernel: conv1 -> gbar -> out1+conv2stats -> gbar -> y ----
// Block (n, oh), thread = channel. S1 (packed i16x2) and out1 stay in REGISTERS.
__global__ __launch_bounds__(256, 4) void rrb_fused(const u32* __restrict__ xb,
                                                    const u32* __restrict__ wp1,
                                                    const u32* __restrict__ wp2,
                                                    const float* __restrict__ pool,
                                                    int* __restrict__ st1_sum, u64* __restrict__ st1_sq,
                                                    int* __restrict__ st2_sum, u64* __restrict__ st2_sq,
                                                    const float* __restrict__ alpha1,
                                                    const float* __restrict__ bn1g, const float* __restrict__ bn1b,
                                                    const float* __restrict__ alpha2,
                                                    const float* __restrict__ bn2g, const float* __restrict__ bn2b,
                                                    const float* __restrict__ pg, const float* __restrict__ pz,
                                                    const float* __restrict__ ps, const float* __restrict__ rsb2,
                                                    float* __restrict__ y, int* __restrict__ bar) {
    __shared__ char shraw[256 * 29 * 4 + OWW * 8 * 4];   // 30592 B
    u32*   xs   = (u32*)shraw;                  // phase A: 3*56*8 u32 = 5376 B
    float* tb   = (float*)shraw;                // phase C: 256*29 f32 transpose (aliases xs)
    u32*   bits = (u32*)(shraw + 256 * 29 * 4); // phase B/C: 28*8 sign-bit words

    int blk = blockIdx.x;
    int n = blk / OHH, oh = blk - n * OHH;
    int c = threadIdx.x;
    int wid = c >> 6, lane = c & 63;

    // -------- Phase A: binary conv1 (3x3,s2,p1) -> packed S in regs + bn1 stats --------
    int r0 = 2 * oh - 1;
    for (int i = c; i < 3 * WW * 8; i += 256) {
        int row = i / (WW * 8);
        int ih = r0 + row;
        xs[i] = (ih >= 0) ? xb[((size_t)(n * HH + ih) * WW) * 8 + (i - row * WW * 8)] : 0u;
    }
    u32 svp[14];    // 28 x i16 conv1 sums, packed
    {
        u32 wreg[72];
        const u32* wsrc = wp1 + (size_t)c * 72;
        #pragma unroll
        for (int i = 0; i < 72; ++i) wreg[i] = wsrc[i];
        __syncthreads();
        bool oh0 = (oh == 0);
        int bsum = 0; long long bsq = 0;
        #pragma unroll
        for (int ow = 0; ow < OWW; ++ow) {
            int S = 0;
            #pragma unroll
            for (int kh = 0; kh < 3; ++kh) {
                bool vkh = !(kh == 0 && oh0);
                #pragma unroll
                for (int kw = 0; kw < 3; ++kw) {
                    int iw = 2 * ow + kw - 1;
                    bool ok = vkh && (iw >= 0);
                    int iwc = iw < 0 ? 0 : iw;
                    const u32* xp = &xs[(kh * WW + iwc) * 8];
                    int p = 0;
                    #pragma unroll
                    for (int j = 0; j < 8; ++j) p += __popc(xp[j] ^ wreg[(kh * 3 + kw) * 8 + j]);
                    S += ok ? (256 - 2 * p) : 0;
                }
            }
            if ((ow & 1) == 0) svp[ow >> 1] = (u32)(S & 0xffff);
            else               svp[ow >> 1] |= (u32)(S & 0xffff) << 16;
            bsum += S;
            bsq += (long long)S * S;
        }
        atomicAdd(&st1_sum[c], bsum);
        atomicAdd(&st1_sq[c], (u64)bsq);
    }

    gbar(bar, FGRID);   // all bn1 stats complete

    // -------- Phase B: out1 = rprelu(bn1(S)+pool) in regs; sign2 bits; bn2 stats --------
    float ov[OWW];
    u32 wr2[8];
    {
        int s1v = __hip_atomic_load(&st1_sum[c], __ATOMIC_RELAXED, __HIP_MEMORY_SCOPE_AGENT);
        u64 q1v = __hip_atomic_load(&st1_sq[c], __ATOMIC_RELAXED, __HIP_MEMORY_SCOPE_AGENT);
        float a1, b1;
        bn_fold_v(s1v, q1v, alpha1[c], bn1g[c], bn1b[c], a1, b1);
        float g = pg[c], z = pz[c], sl = ps[c], b2 = rsb2[c];
        const float* pp = pool + ((size_t)(n * OHH + oh) * OWW) * CC + c;
        #pragma unroll
        for (int k = 0; k < OWW; ++k) {
            int S = (k & 1) ? (((int)svp[k >> 1]) >> 16)
                            : (((int)(svp[k >> 1] << 16)) >> 16);
            float v = a1 * (float)S + b1 + pp[k * CC];
            float xsv = v - g;
            float o = (xsv > 0.f ? xsv : sl * xsv) + z;
            ov[k] = o;
            u64 m = __ballot(o + b2 > 0.f);
            if (lane == 0) *(u64*)&bits[k * 8 + 2 * wid] = m;
        }
        const u32* wsv = wp2 + (size_t)c * 8;
        #pragma unroll
        for (int j = 0; j < 8; ++j) wr2[j] = wsv[j];
        __syncthreads();
        int bsum = 0; long long bsq = 0;
        #pragma unroll
        for (int k = 0; k < OWW; ++k) {
            int p = 0;
            #pragma unroll
            for (int j = 0; j < 8; ++j) p += __popc(bits[k * 8 + j] ^ wr2[j]);
            int S = 256 - 2 * p;
            bsum += S;
            bsq += (long long)S * S;
        }
        atomicAdd(&st2_sum[c], bsum);
        atomicAdd(&st2_sq[c], (u64)bsq);
    }

    gbar(bar, 2 * FGRID);   // all bn2 stats complete

    // -------- Phase C: S2 from LDS bits, y = bn2(S2)+out1, transpose, concat --------
    {
        int s2v = __hip_atomic_load(&st2_sum[c], __ATOMIC_RELAXED, __HIP_MEMORY_SCOPE_AGENT);
        u64 q2v = __hip_atomic_load(&st2_sq[c], __ATOMIC_RELAXED, __HIP_MEMORY_SCOPE_AGENT);
        float a2, b2f;
        bn_fold_v(s2v, q2v, alpha2[c], bn2g[c], bn2b[c], a2, b2f);
        #pragma unroll
        for (int ow = 0; ow < OWW; ++ow) {
            int p = 0;
            #pragma unroll
            for (int j = 0; j < 8; ++j) p += __popc(bits[ow * 8 + j] ^ wr2[j]);
            int S = 256 - 2 * p;
            tb[c * 29 + ow] = a2 * (float)S + b2f + ov[ow];
        }
        __syncthreads();
        #pragma unroll
        for (int it = 0; it < 7; ++it) {
            int idx = it * 256 + c;        // 0..1791 = 256 rows x 7 float4
            int cp = idx / 7, qq = idx - cp * 7;
            const float* lp = &tb[cp * 29 + 4 * qq];
            float4 v = make_float4(lp[0], lp[1], lp[2], lp[3]);
            float* dst = y + ((size_t)(n * 2 * CC + cp) * OHH + oh) * OWW + 4 * qq;
            *(float4*)dst = v;
            *(float4*)(dst + (size_t)CC * OHH * OWW) = v;
        }
    }
}

extern "C" void kernel_launch(void* const* d_in, const int* in_sizes, int n_in,
                              void* d_out, int out_size, void* d_ws, size_t ws_size,
                              hipStream_t stream) {
    const float* x    = (const float*)d_in[0];
    const float* rsb1 = (const float*)d_in[1];
    const float* w1   = (const float*)d_in[2];
    const float* bn1g = (const float*)d_in[3];
    const float* bn1b = (const float*)d_in[4];
    const float* rsb2 = (const float*)d_in[5];
    const float* w2   = (const float*)d_in[6];
    const float* bn2g = (const float*)d_in[7];
    const float* bn2b = (const float*)d_in[8];
    const float* pg   = (const float*)d_in[9];
    const float* pz   = (const float*)d_in[10];
    const float* ps   = (const float*)d_in[11];
    float* y = (float*)d_out;

    char* ws = (char*)d_ws;
    if (ws_size < 28995584) return;

    u32*   wp1    = (u32*)(ws + 0);          // 73728 B
    u32*   wp2    = (u32*)(ws + 73728);      // 8192 B
    float* alpha1 = (float*)(ws + 81920);
    float* alpha2 = (float*)(ws + 82944);
    int*   bar     = (int*)(ws + 84992);     // barrier counter
    int*   st1_sum = (int*)(ws + 88064);     // 1024 B
    u64*   st1_sq  = (u64*)(ws + 89088);     // 2048 B
    int*   st2_sum = (int*)(ws + 91136);     // 1024 B
    u64*   st2_sq  = (u64*)(ws + 92160);     // 2048 B  (stats: 6144 B @88064)
    u32*   xb   = (u32*)(ws + 94208);        // 3,211,264 B   [n][h][w][8]
    float* pool = (float*)(ws + 3305472);    // 25,690,112 B  [pix][256] -> end 28,995,584

    u32* stats_zero = (u32*)(ws + 88064);

    rrb_prep_pack<<<PACKBLKS + 512, 256, 0, stream>>>(x, rsb1, w1, w2, xb, pool,
                                                      wp1, wp2, alpha1, alpha2,
                                                      stats_zero, bar);
    rrb_fused<<<FGRID, 256, 0, stream>>>(xb, wp1, wp2, pool,
                                         st1_sum, st1_sq, st2_sum, st2_sq,
                                         alpha1, bn1g, bn1b, alpha2, bn2g, bn2b,
                                         pg, pz, ps, rsb2, y, bar);
}

// Round 9
// 175.745 us; speedup vs baseline: 1.3769x; 1.3769x over previous
//
#include <hip/hip_runtime.h>
#include <stdint.h>

typedef unsigned long long u64;
typedef uint32_t u32;

#define BB  32
#define CC  256
#define HH  56
#define WW  56
#define OHH 28
#define OWW 28
#define NPIX (BB*OHH*OWW)   // 25088
#define PACKBLKS 3136       // 802816/256
#define FGRID (BB*OHH)      // 896 fused blocks

// ---------------- Kernel 0: pack sign(x+beta1)+avgpool (blocks 0..3135)
//                  + weight prep/alpha/stats+barrier zero (blocks 3136..3647) --------------
__global__ __launch_bounds__(256) void rrb_prep_pack(const float* __restrict__ x,
                                                     const float* __restrict__ rsb1,
                                                     const float* __restrict__ w1,
                                                     const float* __restrict__ w2,
                                                     u32* __restrict__ xb, float* __restrict__ pool,
                                                     u32* __restrict__ wp1, u32* __restrict__ wp2,
                                                     float* __restrict__ alpha1, float* __restrict__ alpha2,
                                                     u32* __restrict__ stats_zero, int* __restrict__ bar) {
    if (blockIdx.x >= PACKBLKS) {
        __shared__ float red[256];
        int pb = blockIdx.x - PACKBLKS;     // 0..511
        int co = pb & 255;
        int t = threadIdx.x;                // ci
        int wid = t >> 6, lane = t & 63;
        if (pb == 0) {
            #pragma unroll
            for (int k = 0; k < 6; ++k) stats_zero[k * 256 + t] = 0u;
            if (t == 0) *bar = 0;
        }
        float asum = 0.f;
        if (pb < 256) {
            const float* wr = w1 + (size_t)co * 2304 + (size_t)t * 9;
            float v[9];
            #pragma unroll
            for (int k = 0; k < 9; ++k) { v[k] = wr[k]; asum += fabsf(v[k]); }
            #pragma unroll
            for (int k = 0; k < 9; ++k) {
                u64 m = __ballot(v[k] > 0.f);
                if (lane == 0)
                    *(u64*)&wp1[((size_t)co * 9 + k) * 8 + 2 * wid] = m;
            }
        } else {
            float v = w2[co * 256 + t];
            asum = fabsf(v);
            u64 m = __ballot(v > 0.f);
            if (lane == 0) *(u64*)&wp2[co * 8 + 2 * wid] = m;
        }
        red[t] = asum; __syncthreads();
        for (int st = 128; st > 0; st >>= 1) {
            if (t < st) red[t] += red[t + st];
            __syncthreads();
        }
        if (t == 0) {
            if (pb < 256) alpha1[co] = red[0] / 2304.f;
            else          alpha2[co] = red[0] / 256.f;
        }
        return;
    }
    // ---- pack path: thread = (j-word, n, oh, ow, s-subslice) ----
    int i = blockIdx.x * 256 + threadIdx.x;   // 802816
    int s  = i & 3;
    int i2 = i >> 2;
    int ow = i2 % OWW;
    int i3 = i2 / OWW;
    int oh = i3 % OHH;
    int i4 = i3 / OHH;
    int n  = i4 & 31;
    int j  = i4 >> 5;
    int c0 = 32 * j + 8 * s;
    const float* base = x + (((size_t)(n * CC + c0) * HH + 2 * oh) * WW + 2 * ow);

    float2 a0[8], a1[8];
    #pragma unroll
    for (int cc = 0; cc < 8; ++cc) {
        const float* p = base + (size_t)cc * (HH * WW);
        a0[cc] = *(const float2*)p;
        a1[cc] = *(const float2*)(p + WW);
    }
    float4 b0 = *(const float4*)&rsb1[c0];
    float4 b1 = *(const float4*)&rsb1[c0 + 4];

    u32 w00 = 0, w01 = 0, w10 = 0, w11 = 0;
    float pv[8];
    #pragma unroll
    for (int cc = 0; cc < 8; ++cc) {
        float b = (cc < 4) ? ((const float*)&b0)[cc] : ((const float*)&b1)[cc - 4];
        w00 |= (u32)(a0[cc].x + b > 0.f) << cc;
        w01 |= (u32)(a0[cc].y + b > 0.f) << cc;
        w10 |= (u32)(a1[cc].x + b > 0.f) << cc;
        w11 |= (u32)(a1[cc].y + b > 0.f) << cc;
        pv[cc] = (a0[cc].x + a0[cc].y + a1[cc].x + a1[cc].y) * 0.25f;
    }
    w00 <<= 8 * s; w01 <<= 8 * s; w10 <<= 8 * s; w11 <<= 8 * s;
    w00 |= __shfl_xor(w00, 1); w00 |= __shfl_xor(w00, 2);
    w01 |= __shfl_xor(w01, 1); w01 |= __shfl_xor(w01, 2);
    w10 |= __shfl_xor(w10, 1); w10 |= __shfl_xor(w10, 2);
    w11 |= __shfl_xor(w11, 1); w11 |= __shfl_xor(w11, 2);

    float* pp = pool + ((size_t)(n * OHH + oh) * OWW + ow) * CC + c0;
    *(float4*)&pp[0] = make_float4(pv[0], pv[1], pv[2], pv[3]);
    *(float4*)&pp[4] = make_float4(pv[4], pv[5], pv[6], pv[7]);

    u32* xo = xb + (((size_t)(n * HH + 2 * oh) * WW + 2 * ow) * 8) + j;
    u32 wsel = (s == 0) ? w00 : (s == 1) ? w01 : (s == 2) ? w10 : w11;
    int off = (s == 0) ? 0 : (s == 1) ? 8 : (s == 2) ? WW * 8 : WW * 8 + 8;
    xo[off] = wsel;
}

// ---- fence-free device spin barrier: RELAXED add + RELAXED polls (no cache invalidates).
// Cross-block data travels ONLY via device-scope atomic RMW/loads (coherent by themselves);
// callers order their stats-RMWs before arrival by consuming the atomicAdd returns.
__device__ __forceinline__ void gbar(int* cnt, int target) {
    __syncthreads();
    if (threadIdx.x == 0) {
        __hip_atomic_fetch_add(cnt, 1, __ATOMIC_RELAXED, __HIP_MEMORY_SCOPE_AGENT);
        int guard = 0;
        while (__hip_atomic_load(cnt, __ATOMIC_RELAXED, __HIP_MEMORY_SCOPE_AGENT) < target) {
            __builtin_amdgcn_s_sleep(16);
            if (++guard > (1 << 22)) break;   // bounded bail-out: fail, don't hang
        }
    }
    __syncthreads();
}

// ---- BN finalize from exact integer stats ----
__device__ __forceinline__ void bn_fold_v(int sv, u64 qv, float al_, float g_, float be_,
                                          float& a, float& b) {
    const double N = (double)NPIX;
    double s = (double)sv;
    double q = (double)qv;
    double mS = s / N;
    double vS = q / N - mS * mS;
    double al = (double)al_;
    double scale = (double)g_ / sqrt(al * al * vS + 1e-5);
    a = (float)(al * scale);
    b = (float)((double)be_ - al * mS * scale);
}

// ---------------- Persistent fused kernel: conv1 -> gbar -> out1+conv2stats -> gbar -> y ----
// Block (n, oh), thread = channel. S1 (packed i16x2) and out1 stay in REGISTERS.
__global__ __launch_bounds__(256, 4) void rrb_fused(const u32* __restrict__ xb,
                                                    const u32* __restrict__ wp1,
                                                    const u32* __restrict__ wp2,
                                                    const float* __restrict__ pool,
                                                    int* __restrict__ st1_sum, u64* __restrict__ st1_sq,
                                                    int* __restrict__ st2_sum, u64* __restrict__ st2_sq,
                                                    const float* __restrict__ alpha1,
                                                    const float* __restrict__ bn1g, const float* __restrict__ bn1b,
                                                    const float* __restrict__ alpha2,
                                                    const float* __restrict__ bn2g, const float* __restrict__ bn2b,
                                                    const float* __restrict__ pg, const float* __restrict__ pz,
                                                    const float* __restrict__ ps, const float* __restrict__ rsb2,
                                                    float* __restrict__ y, int* __restrict__ bar) {
    __shared__ char shraw[256 * 29 * 4 + OWW * 8 * 4];   // 30592 B
    u32*   xs   = (u32*)shraw;                  // phase A: 3*56*8 u32 = 5376 B
    float* tb   = (float*)shraw;                // phase C: 256*29 f32 transpose (aliases xs)
    u32*   bits = (u32*)(shraw + 256 * 29 * 4); // phase B/C: 28*8 sign-bit words

    int blk = blockIdx.x;
    int n = blk / OHH, oh = blk - n * OHH;
    int c = threadIdx.x;
    int wid = c >> 6, lane = c & 63;

    // -------- Phase A: binary conv1 (3x3,s2,p1) -> packed S in regs + bn1 stats --------
    int r0 = 2 * oh - 1;
    for (int i = c; i < 3 * WW * 8; i += 256) {
        int row = i / (WW * 8);
        int ih = r0 + row;
        xs[i] = (ih >= 0) ? xb[((size_t)(n * HH + ih) * WW) * 8 + (i - row * WW * 8)] : 0u;
    }
    u32 svp[14];    // 28 x i16 conv1 sums, packed
    {
        u32 wreg[72];
        const u32* wsrc = wp1 + (size_t)c * 72;
        #pragma unroll
        for (int i = 0; i < 72; ++i) wreg[i] = wsrc[i];
        __syncthreads();
        bool oh0 = (oh == 0);
        int bsum = 0; long long bsq = 0;
        #pragma unroll
        for (int ow = 0; ow < OWW; ++ow) {
            int S = 0;
            #pragma unroll
            for (int kh = 0; kh < 3; ++kh) {
                bool vkh = !(kh == 0 && oh0);
                #pragma unroll
                for (int kw = 0; kw < 3; ++kw) {
                    int iw = 2 * ow + kw - 1;
                    bool ok = vkh && (iw >= 0);
                    int iwc = iw < 0 ? 0 : iw;
                    const u32* xp = &xs[(kh * WW + iwc) * 8];
                    int p = 0;
                    #pragma unroll
                    for (int j = 0; j < 8; ++j) p += __popc(xp[j] ^ wreg[(kh * 3 + kw) * 8 + j]);
                    S += ok ? (256 - 2 * p) : 0;
                }
            }
            if ((ow & 1) == 0) svp[ow >> 1] = (u32)(S & 0xffff);
            else               svp[ow >> 1] |= (u32)(S & 0xffff) << 16;
            bsum += S;
            bsq += (long long)S * S;
        }
        // consume returns -> forces vmcnt wait: RMWs executed at coherent point before arrival
        int o1 = atomicAdd(&st1_sum[c], bsum);
        u64 o2 = atomicAdd(&st1_sq[c], (u64)bsq);
        asm volatile("" :: "v"(o1), "v"((u32)o2), "v"((u32)(o2 >> 32)));
    }

    gbar(bar, FGRID);   // all bn1 stats complete

    // -------- Phase B: out1 = rprelu(bn1(S)+pool) in regs; sign2 bits; bn2 stats --------
    float ov[OWW];
    u32 wr2[8];
    {
        int s1v = __hip_atomic_load(&st1_sum[c], __ATOMIC_RELAXED, __HIP_MEMORY_SCOPE_AGENT);
        u64 q1v = __hip_atomic_load(&st1_sq[c], __ATOMIC_RELAXED, __HIP_MEMORY_SCOPE_AGENT);
        float a1, b1;
        bn_fold_v(s1v, q1v, alpha1[c], bn1g[c], bn1b[c], a1, b1);
        float g = pg[c], z = pz[c], sl = ps[c], b2 = rsb2[c];
        const float* pp = pool + ((size_t)(n * OHH + oh) * OWW) * CC + c;
        #pragma unroll
        for (int k = 0; k < OWW; ++k) {
            int S = (k & 1) ? (((int)svp[k >> 1]) >> 16)
                            : (((int)(svp[k >> 1] << 16)) >> 16);
            float v = a1 * (float)S + b1 + pp[k * CC];
            float xsv = v - g;
            float o = (xsv > 0.f ? xsv : sl * xsv) + z;
            ov[k] = o;
            u64 m = __ballot(o + b2 > 0.f);
            if (lane == 0) *(u64*)&bits[k * 8 + 2 * wid] = m;
        }
        const u32* wsv = wp2 + (size_t)c * 8;
        #pragma unroll
        for (int j = 0; j < 8; ++j) wr2[j] = wsv[j];
        __syncthreads();
        int bsum = 0; long long bsq = 0;
        #pragma unroll
        for (int k = 0; k < OWW; ++k) {
            int p = 0;
            #pragma unroll
            for (int j = 0; j < 8; ++j) p += __popc(bits[k * 8 + j] ^ wr2[j]);
            int S = 256 - 2 * p;
            bsum += S;
            bsq += (long long)S * S;
        }
        int o1 = atomicAdd(&st2_sum[c], bsum);
        u64 o2 = atomicAdd(&st2_sq[c], (u64)bsq);
        asm volatile("" :: "v"(o1), "v"((u32)o2), "v"((u32)(o2 >> 32)));
    }

    gbar(bar, 2 * FGRID);   // all bn2 stats complete

    // -------- Phase C: S2 from LDS bits, y = bn2(S2)+out1, transpose, concat --------
    {
        int s2v = __hip_atomic_load(&st2_sum[c], __ATOMIC_RELAXED, __HIP_MEMORY_SCOPE_AGENT);
        u64 q2v = __hip_atomic_load(&st2_sq[c], __ATOMIC_RELAXED, __HIP_MEMORY_SCOPE_AGENT);
        float a2, b2f;
        bn_fold_v(s2v, q2v, alpha2[c], bn2g[c], bn2b[c], a2, b2f);
        #pragma unroll
        for (int ow = 0; ow < OWW; ++ow) {
            int p = 0;
            #pragma unroll
            for (int j = 0; j < 8; ++j) p += __popc(bits[ow * 8 + j] ^ wr2[j]);
            int S = 256 - 2 * p;
            tb[c * 29 + ow] = a2 * (float)S + b2f + ov[ow];
        }
        __syncthreads();
        #pragma unroll
        for (int it = 0; it < 7; ++it) {
            int idx = it * 256 + c;        // 0..1791 = 256 rows x 7 float4
            int cp = idx / 7, qq = idx - cp * 7;
            const float* lp = &tb[cp * 29 + 4 * qq];
            float4 v = make_float4(lp[0], lp[1], lp[2], lp[3]);
            float* dst = y + ((size_t)(n * 2 * CC + cp) * OHH + oh) * OWW + 4 * qq;
            *(float4*)dst = v;
            *(float4*)(dst + (size_t)CC * OHH * OWW) = v;
        }
    }
}

extern "C" void kernel_launch(void* const* d_in, const int* in_sizes, int n_in,
                              void* d_out, int out_size, void* d_ws, size_t ws_size,
                              hipStream_t stream) {
    const float* x    = (const float*)d_in[0];
    const float* rsb1 = (const float*)d_in[1];
    const float* w1   = (const float*)d_in[2];
    const float* bn1g = (const float*)d_in[3];
    const float* bn1b = (const float*)d_in[4];
    const float* rsb2 = (const float*)d_in[5];
    const float* w2   = (const float*)d_in[6];
    const float* bn2g = (const float*)d_in[7];
    const float* bn2b = (const float*)d_in[8];
    const float* pg   = (const float*)d_in[9];
    const float* pz   = (const float*)d_in[10];
    const float* ps   = (const float*)d_in[11];
    float* y = (float*)d_out;

    char* ws = (char*)d_ws;
    if (ws_size < 28995584) return;

    u32*   wp1    = (u32*)(ws + 0);          // 73728 B
    u32*   wp2    = (u32*)(ws + 73728);      // 8192 B
    float* alpha1 = (float*)(ws + 81920);
    float* alpha2 = (float*)(ws + 82944);
    int*   bar     = (int*)(ws + 84992);     // barrier counter
    int*   st1_sum = (int*)(ws + 88064);     // 1024 B
    u64*   st1_sq  = (u64*)(ws + 89088);     // 2048 B
    int*   st2_sum = (int*)(ws + 91136);     // 1024 B
    u64*   st2_sq  = (u64*)(ws + 92160);     // 2048 B  (stats: 6144 B @88064)
    u32*   xb   = (u32*)(ws + 94208);        // 3,211,264 B   [n][h][w][8]
    float* pool = (float*)(ws + 3305472);    // 25,690,112 B  [pix][256] -> end 28,995,584

    u32* stats_zero = (u32*)(ws + 88064);

    rrb_prep_pack<<<PACKBLKS + 512, 256, 0, stream>>>(x, rsb1, w1, w2, xb, pool,
                                                      wp1, wp2, alpha1, alpha2,
                                                      stats_zero, bar);
    rrb_fused<<<FGRID, 256, 0, stream>>>(xb, wp1, wp2, pool,
                                         st1_sum, st1_sq, st2_sum, st2_sq,
                                         alpha1, bn1g, bn1b, alpha2, bn2g, bn2b,
                                         pg, pz, ps, rsb2, y, bar);
}